// Round 16
// baseline (258.096 us; speedup 1.0000x reference)
//
#include <hip/hip_runtime.h>
#include <hip/hip_bf16.h>

#define BN 16384
#define NPTS 8192
#define KNN 16

typedef __attribute__((ext_vector_type(8))) short bf16x8;
typedef __attribute__((ext_vector_type(4))) float f32x4;
typedef __attribute__((ext_vector_type(4))) unsigned short u16x4;

static __device__ __forceinline__ unsigned short f2bf(float f) {
    union { float f; unsigned u; } v; v.f = f;
    unsigned r = v.u + 0x7fffu + ((v.u >> 16) & 1u);
    return (unsigned short)(r >> 16);
}

static __device__ __forceinline__ float bf2f(unsigned short u) {
    union { unsigned u; float f; } v; v.u = ((unsigned)u) << 16; return v.f;
}

static __device__ __forceinline__ float rfl(float v) {
    return __int_as_float(__builtin_amdgcn_readfirstlane(__float_as_int(v)));
}

// ---------------- pack xyz + prep qkv weights (fused; role by blockIdx) ------
__global__ __launch_bounds__(256) void pack_prep(const float* __restrict__ xyz,
                                                 float4* __restrict__ xyz4,
                                                 const float* __restrict__ wq,
                                                 const float* __restrict__ wk,
                                                 const float* __restrict__ wv,
                                                 unsigned short* __restrict__ wbf) {
    if (blockIdx.x < 64) {
        int i = blockIdx.x * 256 + threadIdx.x;
        float x = xyz[i * 3 + 0], y = xyz[i * 3 + 1], z = xyz[i * 3 + 2];
        xyz4[i] = make_float4(x, y, z, x * x + y * y + z * z);
    } else {
        int mat = blockIdx.x - 64;
        const float* src = (mat == 0) ? wq : (mat == 1) ? wk : wv;
        unsigned short* dst = wbf + mat * 4096;
        for (int i = threadIdx.x; i < 4096; i += 256) {
            int k = i >> 6, n = i & 63;
            dst[n * 64 + k] = f2bf(src[i]);
        }
    }
}

// ---------------- fused KNN + QKV (role by blockIdx) ----------------
__global__ __launch_bounds__(256, 8) void knnqkv_kernel(
    const float4* __restrict__ xyz4, int* __restrict__ knn_idx,
    const float* __restrict__ feats, const unsigned short* __restrict__ wbf,
    float* __restrict__ Q, float* __restrict__ Kf, float* __restrict__ Vf) {
    __shared__ float wmaxs[4][8];
    __shared__ int   cnt[8];
    __shared__ float ckey[8 * 256];
    __shared__ int   cidx[8 * 256];
    int tid = threadIdx.x, lane = tid & 63, w = tid >> 6;

    if (blockIdx.x < 256) {
        int quad = lane >> 4, col = lane & 15;
        int row0 = blockIdx.x * 64 + w * 16;
        bf16x8 a0, a1;
        {
            const float* fp = feats + (row0 + col) * 64 + quad * 8;
            float4 x0 = *(const float4*)fp,        x1 = *(const float4*)(fp + 4);
            float4 x2 = *(const float4*)(fp + 32), x3 = *(const float4*)(fp + 36);
            a0[0] = (short)f2bf(x0.x); a0[1] = (short)f2bf(x0.y); a0[2] = (short)f2bf(x0.z); a0[3] = (short)f2bf(x0.w);
            a0[4] = (short)f2bf(x1.x); a0[5] = (short)f2bf(x1.y); a0[6] = (short)f2bf(x1.z); a0[7] = (short)f2bf(x1.w);
            a1[0] = (short)f2bf(x2.x); a1[1] = (short)f2bf(x2.y); a1[2] = (short)f2bf(x2.z); a1[3] = (short)f2bf(x2.w);
            a1[4] = (short)f2bf(x3.x); a1[5] = (short)f2bf(x3.y); a1[6] = (short)f2bf(x3.z); a1[7] = (short)f2bf(x3.w);
        }
        float* outs[3] = {Q, Kf, Vf};
#pragma unroll
        for (int mat = 0; mat < 3; mat++) {
            float* out = outs[mat];
#pragma unroll
            for (int nt = 0; nt < 4; nt++) {
                const unsigned short* p0 = wbf + mat * 4096 + (nt * 16 + col) * 64 + quad * 8;
                bf16x8 b0 = *(const bf16x8*)p0;
                bf16x8 b1 = *(const bf16x8*)(p0 + 32);
                f32x4 acc = {0.f, 0.f, 0.f, 0.f};
                acc = __builtin_amdgcn_mfma_f32_16x16x32_bf16(a0, b0, acc, 0, 0, 0);
                acc = __builtin_amdgcn_mfma_f32_16x16x32_bf16(a1, b1, acc, 0, 0, 0);
#pragma unroll
                for (int r = 0; r < 4; r++)
                    out[(row0 + quad * 4 + r) * 64 + nt * 16 + col] = acc[r];
            }
        }
        return;
    }

    int r0 = (blockIdx.x - 256) * 8;
    int b = r0 >> 13;
    const float4* __restrict__ base = xyz4 + b * NPTS;

    float qx[8], qy[8], qz[8], minv[8];
#pragma unroll
    for (int rr = 0; rr < 8; rr++) {
        float4 q = xyz4[r0 + rr];
        qx[rr] = -2.f * q.x; qy[rr] = -2.f * q.y; qz[rr] = -2.f * q.z;
        minv[rr] = 3e38f;
    }
    if (tid < 8) cnt[tid] = 0;

#pragma unroll 4
    for (int i = 0; i < 32; i++) {
        float4 c = base[tid + (i << 8)];
#pragma unroll
        for (int rr = 0; rr < 8; rr++) {
            float d = fmaf(qx[rr], c.x, fmaf(qy[rr], c.y, fmaf(qz[rr], c.z, c.w)));
            minv[rr] = fminf(minv[rr], d);
        }
    }

#pragma unroll
    for (int rr = 0; rr < 8; rr++) {
        float v = minv[rr];
        v = fminf(v, __shfl_xor(v, 1, 64));
        v = fminf(v, __shfl_xor(v, 2, 64));
        v = fminf(v, __shfl_xor(v, 4, 64));
        v = fminf(v, __shfl_xor(v, 8, 64));
        v = fmaxf(v, __shfl_xor(v, 16, 64));
        v = fmaxf(v, __shfl_xor(v, 32, 64));
        if (lane == 0) wmaxs[w][rr] = v;
    }
    __syncthreads();
    float T[8];
#pragma unroll
    for (int rr = 0; rr < 8; rr++)
        T[rr] = rfl(fmaxf(fmaxf(wmaxs[0][rr], wmaxs[1][rr]),
                          fmaxf(wmaxs[2][rr], wmaxs[3][rr])));

#pragma unroll 2
    for (int i = 0; i < 32; i++) {
        float4 c = base[tid + (i << 8)];
#pragma unroll
        for (int rr = 0; rr < 8; rr++) {
            float d = fmaf(qx[rr], c.x, fmaf(qy[rr], c.y, fmaf(qz[rr], c.z, c.w)));
            if (d <= T[rr]) {
                int p = atomicAdd(&cnt[rr], 1);
                if (p < 256) { ckey[rr * 256 + p] = d; cidx[rr * 256 + p] = tid + (i << 8); }
            }
        }
    }
    __syncthreads();

    for (int rr = w; rr < 8; rr += 4) {
        int cc = min(cnt[rr], 256);
        for (int s = lane; s < cc; s += 64) {
            float myk = ckey[rr * 256 + s]; int myi = cidx[rr * 256 + s];
            int rank = 0;
            for (int j2 = 0; j2 < cc; j2++) {
                float kj = ckey[rr * 256 + j2]; int ij = cidx[rr * 256 + j2];
                rank += (kj < myk || (kj == myk && ij < myi)) ? 1 : 0;
            }
            if (rank < 16) knn_idx[(r0 + rr) * 16 + rank] = myi;
        }
    }
}

// ---------------- fused attention + BN partial sums ----------------
// K/V gathers staged through sA (dead between GEMM A-frag loads): 64 scalar
// global gathers -> 16 float4 gathers per lane, each for K and V.
__global__ __launch_bounds__(256, 2) void attn_mfma(
    const float4* __restrict__ xyz4, const int* __restrict__ knn_idx,
    const float* __restrict__ Q, const float* __restrict__ Kf, const float* __restrict__ Vf,
    const float* __restrict__ feats,
    const float* __restrict__ dw1, const float* __restrict__ db1,
    const float* __restrict__ dw2, const float* __restrict__ db2,
    const float* __restrict__ gw1, const float* __restrict__ gb1,
    const float* __restrict__ gw2,
    float* __restrict__ res, float* __restrict__ accum) {
    __shared__ __align__(16) unsigned short sWd2[64 * 68];
    __shared__ __align__(16) unsigned short sWg1[64 * 68];
    __shared__ __align__(16) unsigned short sWg2[64 * 68];
    __shared__ __align__(16) unsigned short sA[256 * 72];
    __shared__ int sidx[256];
    __shared__ float sdw1[256];

    int tid = threadIdx.x;
    int w = tid >> 6, lane = tid & 63, quad = lane >> 4, col = lane & 15;
    int r0 = blockIdx.x * 16;

    for (int i = tid; i < 4096; i += 256) {
        int e = i >> 6, c = i & 63;
        sWd2[c * 68 + e] = f2bf(dw2[i]);
        sWg1[c * 68 + e] = f2bf(gw1[i]);
        sWg2[c * 68 + e] = f2bf(gw2[i]);
    }
    if (tid < 192) sdw1[tid] = dw1[tid];
    else sdw1[tid] = db1[tid - 192];
    {
        int brow = r0 + (tid >> 4);
        int b = brow >> 13;
        sidx[tid] = b * NPTS + knn_idx[brow * 16 + (tid & 15)];
    }
    __syncthreads();

    // H1 = relu(rel @ dw1 + db1), thread per m-row, bf16 into sA
    {
        int m = tid;
        int brow = r0 + (m >> 4);
        float4 p = xyz4[brow];
        float4 nb = xyz4[sidx[m]];
        float rx = p.x - nb.x, ry = p.y - nb.y, rz = p.z - nb.z;
        for (int c0 = 0; c0 < 64; c0 += 8) {
            bf16x8 v;
#pragma unroll
            for (int cc = 0; cc < 8; cc++) {
                int c = c0 + cc;
                float h = sdw1[192 + c] + rx * sdw1[c] + ry * sdw1[64 + c] + rz * sdw1[128 + c];
                v[cc] = (short)f2bf(fmaxf(h, 0.f));
            }
            *(bf16x8*)&sA[m * 72 + c0] = v;
        }
    }

    int m0 = w * 64;
    bf16x8 af[4][2];

    // GEMM2 A-frags into regs; then sA rows are dead -> stage K there.
#pragma unroll
    for (int mt = 0; mt < 4; mt++)
#pragma unroll
        for (int k2 = 0; k2 < 2; k2++)
            af[mt][k2] = *(const bf16x8*)&sA[(m0 + mt * 16 + col) * 72 + quad * 8 + k2 * 32];

    // stage gathered K rows (lane L owns LDS row m0+L), bf16 in-place
    {
        int m = m0 + lane;
        const float* kp = Kf + sidx[m] * 64;
#pragma unroll
        for (int c0 = 0; c0 < 64; c0 += 8) {
            float4 x0 = *(const float4*)(kp + c0);
            float4 x1 = *(const float4*)(kp + c0 + 4);
            bf16x8 v;
            v[0] = (short)f2bf(x0.x); v[1] = (short)f2bf(x0.y); v[2] = (short)f2bf(x0.z); v[3] = (short)f2bf(x0.w);
            v[4] = (short)f2bf(x1.x); v[5] = (short)f2bf(x1.y); v[6] = (short)f2bf(x1.z); v[7] = (short)f2bf(x1.w);
            *(bf16x8*)&sA[m * 72 + c0] = v;
        }
    }

    f32x4 pos[4][4];
#pragma unroll
    for (int nt = 0; nt < 4; nt++) {
        float bias = db2[nt * 16 + col];
        bf16x8 b0, b1;
        {
            const unsigned short* p0 = &sWd2[(nt * 16 + col) * 68 + quad * 8];
            u16x4 l0 = *(const u16x4*)p0, h0 = *(const u16x4*)(p0 + 4);
            u16x4 l1 = *(const u16x4*)(p0 + 32), h1 = *(const u16x4*)(p0 + 36);
#pragma unroll
            for (int z = 0; z < 4; z++) { b0[z] = (short)l0[z]; b0[z+4] = (short)h0[z]; b1[z] = (short)l1[z]; b1[z+4] = (short)h1[z]; }
        }
#pragma unroll
        for (int mt = 0; mt < 4; mt++) {
            f32x4 acc = {bias, bias, bias, bias};
            acc = __builtin_amdgcn_mfma_f32_16x16x32_bf16(af[mt][0], b0, acc, 0, 0, 0);
            acc = __builtin_amdgcn_mfma_f32_16x16x32_bf16(af[mt][1], b1, acc, 0, 0, 0);
            pos[mt][nt] = acc;
        }
    }

    // tvec = q - k(LDS) + pos -> bf16 in-place (wave-private rows)
#pragma unroll
    for (int mt = 0; mt < 4; mt++) {
        int row = r0 + w * 4 + mt;
#pragma unroll
        for (int nt = 0; nt < 4; nt++) {
            int c = nt * 16 + col;
            float qv = Q[row * 64 + c];
#pragma unroll
            for (int r = 0; r < 4; r++) {
                int adr = (m0 + mt * 16 + quad * 4 + r) * 72 + c;
                float kv = bf2f(sA[adr]);
                float tv = qv - kv + pos[mt][nt][r];
                sA[adr] = f2bf(tv);
            }
        }
    }

    // GEMM3: h2 = relu(tvec @ gw1 + gb1) -> bf16 into sA
#pragma unroll
    for (int mt = 0; mt < 4; mt++)
#pragma unroll
        for (int k2 = 0; k2 < 2; k2++)
            af[mt][k2] = *(const bf16x8*)&sA[(m0 + mt * 16 + col) * 72 + quad * 8 + k2 * 32];

    f32x4 cc4[4][4];
#pragma unroll
    for (int nt = 0; nt < 4; nt++) {
        float bias = gb1[nt * 16 + col];
        bf16x8 b0, b1;
        {
            const unsigned short* p0 = &sWg1[(nt * 16 + col) * 68 + quad * 8];
            u16x4 l0 = *(const u16x4*)p0, h0 = *(const u16x4*)(p0 + 4);
            u16x4 l1 = *(const u16x4*)(p0 + 32), h1 = *(const u16x4*)(p0 + 36);
#pragma unroll
            for (int z = 0; z < 4; z++) { b0[z] = (short)l0[z]; b0[z+4] = (short)h0[z]; b1[z] = (short)l1[z]; b1[z+4] = (short)h1[z]; }
        }
#pragma unroll
        for (int mt = 0; mt < 4; mt++) {
            f32x4 acc = {bias, bias, bias, bias};
            acc = __builtin_amdgcn_mfma_f32_16x16x32_bf16(af[mt][0], b0, acc, 0, 0, 0);
            acc = __builtin_amdgcn_mfma_f32_16x16x32_bf16(af[mt][1], b1, acc, 0, 0, 0);
            cc4[mt][nt] = acc;
        }
    }
#pragma unroll
    for (int mt = 0; mt < 4; mt++)
#pragma unroll
        for (int nt = 0; nt < 4; nt++)
#pragma unroll
            for (int r = 0; r < 4; r++)
                sA[(m0 + mt * 16 + quad * 4 + r) * 72 + nt * 16 + col] = f2bf(fmaxf(cc4[mt][nt][r], 0.f));

    // GEMM4 A-frags; then stage V into the dead sA rows
#pragma unroll
    for (int mt = 0; mt < 4; mt++)
#pragma unroll
        for (int k2 = 0; k2 < 2; k2++)
            af[mt][k2] = *(const bf16x8*)&sA[(m0 + mt * 16 + col) * 72 + quad * 8 + k2 * 32];

    {
        int m = m0 + lane;
        const float* vp = Vf + sidx[m] * 64;
#pragma unroll
        for (int c0 = 0; c0 < 64; c0 += 8) {
            float4 x0 = *(const float4*)(vp + c0);
            float4 x1 = *(const float4*)(vp + c0 + 4);
            bf16x8 v;
            v[0] = (short)f2bf(x0.x); v[1] = (short)f2bf(x0.y); v[2] = (short)f2bf(x0.z); v[3] = (short)f2bf(x0.w);
            v[4] = (short)f2bf(x1.x); v[5] = (short)f2bf(x1.y); v[6] = (short)f2bf(x1.z); v[7] = (short)f2bf(x1.w);
            *(bf16x8*)&sA[m * 72 + c0] = v;
        }
    }

#pragma unroll
    for (int nt = 0; nt < 4; nt++) {
        bf16x8 b0, b1;
        {
            const unsigned short* p0 = &sWg2[(nt * 16 + col) * 68 + quad * 8];
            u16x4 l0 = *(const u16x4*)p0, h0 = *(const u16x4*)(p0 + 4);
            u16x4 l1 = *(const u16x4*)(p0 + 32), h1 = *(const u16x4*)(p0 + 36);
#pragma unroll
            for (int z = 0; z < 4; z++) { b0[z] = (short)l0[z]; b0[z+4] = (short)h0[z]; b1[z] = (short)l1[z]; b1[z+4] = (short)h1[z]; }
        }
#pragma unroll
        for (int mt = 0; mt < 4; mt++) {
            f32x4 acc = {0.f, 0.f, 0.f, 0.f};
            acc = __builtin_amdgcn_mfma_f32_16x16x32_bf16(af[mt][0], b0, acc, 0, 0, 0);
            acc = __builtin_amdgcn_mfma_f32_16x16x32_bf16(af[mt][1], b1, acc, 0, 0, 0);
            cc4[mt][nt] = acc;
        }
    }

    // softmax over 16 neighbors + weighted sum of (V(LDS)+pos) + residual + BN
    float bs[4] = {0.f, 0.f, 0.f, 0.f}, bq[4] = {0.f, 0.f, 0.f, 0.f};
#pragma unroll
    for (int mt = 0; mt < 4; mt++) {
        int row = r0 + w * 4 + mt;
#pragma unroll
        for (int nt = 0; nt < 4; nt++) {
            int c = nt * 16 + col;
            f32x4 a = cc4[mt][nt];
            float mx = fmaxf(fmaxf(a[0], a[1]), fmaxf(a[2], a[3]));
            mx = fmaxf(mx, __shfl_xor(mx, 16, 64));
            mx = fmaxf(mx, __shfl_xor(mx, 32, 64));
            float es = 0.f, ws = 0.f;
#pragma unroll
            for (int r = 0; r < 4; r++) {
                float e = __expf(a[r] - mx);
                float vv = bf2f(sA[(m0 + mt * 16 + quad * 4 + r) * 72 + c]) + pos[mt][nt][r];
                es += e;
                ws = fmaf(e, vv, ws);
            }
            es += __shfl_xor(es, 16, 64); es += __shfl_xor(es, 32, 64);
            ws += __shfl_xor(ws, 16, 64); ws += __shfl_xor(ws, 32, 64);
            if (quad == 0) {
                float v = ws / es + feats[row * 64 + c];
                res[row * 64 + c] = v;
                bs[nt] += v;
                bq[nt] = fmaf(v, v, bq[nt]);
            }
        }
    }

    __syncthreads();
    float* fbuf = (float*)sA;
    if (quad == 0) {
#pragma unroll
        for (int nt = 0; nt < 4; nt++) {
            int c = nt * 16 + col;
            fbuf[w * 64 + c] = bs[nt];
            fbuf[256 + w * 64 + c] = bq[nt];
        }
    }
    __syncthreads();
    if (tid < 64) {
        float s = fbuf[tid] + fbuf[64 + tid] + fbuf[128 + tid] + fbuf[192 + tid];
        atomicAdd(&accum[tid], s);
    } else if (tid < 128) {
        int c = tid - 64;
        float q = fbuf[256 + c] + fbuf[320 + c] + fbuf[384 + c] + fbuf[448 + c];
        atomicAdd(&accum[64 + c], q);
    }
}

// ---------------- batchnorm apply + fp32 output ----------------
__global__ __launch_bounds__(256) void norm_kernel(const float* __restrict__ res,
                                                   const float* __restrict__ accum,
                                                   const float* __restrict__ bng,
                                                   const float* __restrict__ bnb,
                                                   float* __restrict__ out) {
    int i = blockIdx.x * 256 + threadIdx.x;
    int c = i & 63;
    float mean = accum[c] * (1.f / 16384.f);
    float var = accum[64 + c] * (1.f / 16384.f) - mean * mean;
    float sc = rsqrtf(var + 1e-5f) * bng[c];
    out[i] = fmaf(res[i] - mean, sc, bnb[c]);
}

extern "C" void kernel_launch(void* const* d_in, const int* in_sizes, int n_in,
                              void* d_out, int out_size, void* d_ws, size_t ws_size,
                              hipStream_t stream) {
    const float* xyz  = (const float*)d_in[0];
    const float* feats = (const float*)d_in[1];
    const float* w_qs = (const float*)d_in[2];
    const float* w_ks = (const float*)d_in[3];
    const float* w_vs = (const float*)d_in[4];
    const float* dw1 = (const float*)d_in[5];
    const float* db1 = (const float*)d_in[6];
    const float* dw2 = (const float*)d_in[7];
    const float* db2 = (const float*)d_in[8];
    const float* gw1 = (const float*)d_in[9];
    const float* gb1 = (const float*)d_in[10];
    const float* gw2 = (const float*)d_in[11];
    const float* bng = (const float*)d_in[13];
    const float* bnb = (const float*)d_in[14];

    char* ws = (char*)d_ws;
    float4* xyz4 = (float4*)ws;                        // 256 KB
    int* knn    = (int*)(ws + 262144);                 // 1 MB
    float* Q    = (float*)(ws + 1310720);              // 4 MB
    float* Kf   = (float*)(ws + 5505024);              // 4 MB
    float* Vf   = (float*)(ws + 9699328);              // 4 MB
    float* res  = (float*)(ws + 13893632);             // 4 MB
    float* accum = (float*)(ws + 18087936);            // 512 B
    unsigned short* wbf = (unsigned short*)(ws + 18088448); // 24 KB bf16 qkv weights

    hipMemsetAsync(accum, 0, 512, stream);
    pack_prep<<<67, 256, 0, stream>>>(xyz, xyz4, w_qs, w_ks, w_vs, wbf);
    knnqkv_kernel<<<2304, 256, 0, stream>>>(xyz4, knn, feats, wbf, Q, Kf, Vf);
    attn_mfma<<<1024, 256, 0, stream>>>(xyz4, knn, Q, Kf, Vf, feats,
                                        dw1, db1, dw2, db2, gw1, gb1, gw2, res, accum);
    norm_kernel<<<4096, 256, 0, stream>>>(res, accum, bng, bnb, (float*)d_out);
}

// Round 17
// 249.659 us; speedup vs baseline: 1.0338x; 1.0338x over previous
//
#include <hip/hip_runtime.h>
#include <hip/hip_bf16.h>

#define BN 16384
#define NPTS 8192
#define KNN 16

typedef __attribute__((ext_vector_type(8))) short bf16x8;
typedef __attribute__((ext_vector_type(4))) float f32x4;
typedef __attribute__((ext_vector_type(4))) unsigned short u16x4;

static __device__ __forceinline__ unsigned short f2bf(float f) {
    union { float f; unsigned u; } v; v.f = f;
    unsigned r = v.u + 0x7fffu + ((v.u >> 16) & 1u);
    return (unsigned short)(r >> 16);
}

static __device__ __forceinline__ float rfl(float v) {
    return __int_as_float(__builtin_amdgcn_readfirstlane(__float_as_int(v)));
}

// ---------------- pack xyz + prep qkv weights (fused; role by blockIdx) ------
__global__ __launch_bounds__(256) void pack_prep(const float* __restrict__ xyz,
                                                 float4* __restrict__ xyz4,
                                                 const float* __restrict__ wq,
                                                 const float* __restrict__ wk,
                                                 const float* __restrict__ wv,
                                                 unsigned short* __restrict__ wbf) {
    if (blockIdx.x < 64) {
        int i = blockIdx.x * 256 + threadIdx.x;
        float x = xyz[i * 3 + 0], y = xyz[i * 3 + 1], z = xyz[i * 3 + 2];
        xyz4[i] = make_float4(x, y, z, x * x + y * y + z * z);
    } else {
        int mat = blockIdx.x - 64;
        const float* src = (mat == 0) ? wq : (mat == 1) ? wk : wv;
        unsigned short* dst = wbf + mat * 4096;
        for (int i = threadIdx.x; i < 4096; i += 256) {
            int k = i >> 6, n = i & 63;
            dst[n * 64 + k] = f2bf(src[i]);
        }
    }
}

// ---------------- fused KNN + QKV (role by blockIdx) ----------------
__global__ __launch_bounds__(256, 8) void knnqkv_kernel(
    const float4* __restrict__ xyz4, int* __restrict__ knn_idx,
    const float* __restrict__ feats, const unsigned short* __restrict__ wbf,
    float* __restrict__ Q, float* __restrict__ Kf, float* __restrict__ Vf) {
    __shared__ float wmaxs[4][8];
    __shared__ int   cnt[8];
    __shared__ float ckey[8 * 256];
    __shared__ int   cidx[8 * 256];
    int tid = threadIdx.x, lane = tid & 63, w = tid >> 6;

    if (blockIdx.x < 256) {
        int quad = lane >> 4, col = lane & 15;
        int row0 = blockIdx.x * 64 + w * 16;
        bf16x8 a0, a1;
        {
            const float* fp = feats + (row0 + col) * 64 + quad * 8;
            float4 x0 = *(const float4*)fp,        x1 = *(const float4*)(fp + 4);
            float4 x2 = *(const float4*)(fp + 32), x3 = *(const float4*)(fp + 36);
            a0[0] = (short)f2bf(x0.x); a0[1] = (short)f2bf(x0.y); a0[2] = (short)f2bf(x0.z); a0[3] = (short)f2bf(x0.w);
            a0[4] = (short)f2bf(x1.x); a0[5] = (short)f2bf(x1.y); a0[6] = (short)f2bf(x1.z); a0[7] = (short)f2bf(x1.w);
            a1[0] = (short)f2bf(x2.x); a1[1] = (short)f2bf(x2.y); a1[2] = (short)f2bf(x2.z); a1[3] = (short)f2bf(x2.w);
            a1[4] = (short)f2bf(x3.x); a1[5] = (short)f2bf(x3.y); a1[6] = (short)f2bf(x3.z); a1[7] = (short)f2bf(x3.w);
        }
        float* outs[3] = {Q, Kf, Vf};
#pragma unroll
        for (int mat = 0; mat < 3; mat++) {
            float* out = outs[mat];
#pragma unroll
            for (int nt = 0; nt < 4; nt++) {
                const unsigned short* p0 = wbf + mat * 4096 + (nt * 16 + col) * 64 + quad * 8;
                bf16x8 b0 = *(const bf16x8*)p0;
                bf16x8 b1 = *(const bf16x8*)(p0 + 32);
                f32x4 acc = {0.f, 0.f, 0.f, 0.f};
                acc = __builtin_amdgcn_mfma_f32_16x16x32_bf16(a0, b0, acc, 0, 0, 0);
                acc = __builtin_amdgcn_mfma_f32_16x16x32_bf16(a1, b1, acc, 0, 0, 0);
#pragma unroll
                for (int r = 0; r < 4; r++)
                    out[(row0 + quad * 4 + r) * 64 + nt * 16 + col] = acc[r];
            }
        }
        return;
    }

    int r0 = (blockIdx.x - 256) * 8;
    int b = r0 >> 13;
    const float4* __restrict__ base = xyz4 + b * NPTS;

    float qx[8], qy[8], qz[8], minv[8];
#pragma unroll
    for (int rr = 0; rr < 8; rr++) {
        float4 q = xyz4[r0 + rr];
        qx[rr] = -2.f * q.x; qy[rr] = -2.f * q.y; qz[rr] = -2.f * q.z;
        minv[rr] = 3e38f;
    }
    if (tid < 8) cnt[tid] = 0;

#pragma unroll 4
    for (int i = 0; i < 32; i++) {
        float4 c = base[tid + (i << 8)];
#pragma unroll
        for (int rr = 0; rr < 8; rr++) {
            float d = fmaf(qx[rr], c.x, fmaf(qy[rr], c.y, fmaf(qz[rr], c.z, c.w)));
            minv[rr] = fminf(minv[rr], d);
        }
    }

#pragma unroll
    for (int rr = 0; rr < 8; rr++) {
        float v = minv[rr];
        v = fminf(v, __shfl_xor(v, 1, 64));
        v = fminf(v, __shfl_xor(v, 2, 64));
        v = fminf(v, __shfl_xor(v, 4, 64));
        v = fminf(v, __shfl_xor(v, 8, 64));
        v = fmaxf(v, __shfl_xor(v, 16, 64));
        v = fmaxf(v, __shfl_xor(v, 32, 64));
        if (lane == 0) wmaxs[w][rr] = v;
    }
    __syncthreads();
    float T[8];
#pragma unroll
    for (int rr = 0; rr < 8; rr++)
        T[rr] = rfl(fmaxf(fmaxf(wmaxs[0][rr], wmaxs[1][rr]),
                          fmaxf(wmaxs[2][rr], wmaxs[3][rr])));

#pragma unroll 2
    for (int i = 0; i < 32; i++) {
        float4 c = base[tid + (i << 8)];
#pragma unroll
        for (int rr = 0; rr < 8; rr++) {
            float d = fmaf(qx[rr], c.x, fmaf(qy[rr], c.y, fmaf(qz[rr], c.z, c.w)));
            if (d <= T[rr]) {
                int p = atomicAdd(&cnt[rr], 1);
                if (p < 256) { ckey[rr * 256 + p] = d; cidx[rr * 256 + p] = tid + (i << 8); }
            }
        }
    }
    __syncthreads();

    for (int rr = w; rr < 8; rr += 4) {
        int cc = min(cnt[rr], 256);
        for (int s = lane; s < cc; s += 64) {
            float myk = ckey[rr * 256 + s]; int myi = cidx[rr * 256 + s];
            int rank = 0;
            for (int j2 = 0; j2 < cc; j2++) {
                float kj = ckey[rr * 256 + j2]; int ij = cidx[rr * 256 + j2];
                rank += (kj < myk || (kj == myk && ij < myi)) ? 1 : 0;
            }
            if (rank < 16) knn_idx[(r0 + rr) * 16 + rank] = myi;
        }
    }
}

// ---------------- fused attention + BN partial sums (r15 known-good) ---------
__global__ __launch_bounds__(256, 2) void attn_mfma(
    const float4* __restrict__ xyz4, const int* __restrict__ knn_idx,
    const float* __restrict__ Q, const float* __restrict__ Kf, const float* __restrict__ Vf,
    const float* __restrict__ feats,
    const float* __restrict__ dw1, const float* __restrict__ db1,
    const float* __restrict__ dw2, const float* __restrict__ db2,
    const float* __restrict__ gw1, const float* __restrict__ gb1,
    const float* __restrict__ gw2,
    float* __restrict__ res, float* __restrict__ accum) {
    __shared__ __align__(16) unsigned short sWd2[64 * 68];
    __shared__ __align__(16) unsigned short sWg1[64 * 68];
    __shared__ __align__(16) unsigned short sWg2[64 * 68];
    __shared__ __align__(16) unsigned short sA[256 * 72];
    __shared__ int sidx[256];
    __shared__ float sdw1[256];

    int tid = threadIdx.x;
    int w = tid >> 6, lane = tid & 63, quad = lane >> 4, col = lane & 15;
    int r0 = blockIdx.x * 16;

    for (int i = tid; i < 4096; i += 256) {
        int e = i >> 6, c = i & 63;
        sWd2[c * 68 + e] = f2bf(dw2[i]);
        sWg1[c * 68 + e] = f2bf(gw1[i]);
        sWg2[c * 68 + e] = f2bf(gw2[i]);
    }
    if (tid < 192) sdw1[tid] = dw1[tid];
    else sdw1[tid] = db1[tid - 192];
    {
        int brow = r0 + (tid >> 4);
        int b = brow >> 13;
        sidx[tid] = b * NPTS + knn_idx[brow * 16 + (tid & 15)];
    }
    __syncthreads();

    {
        int m = tid;
        int brow = r0 + (m >> 4);
        float4 p = xyz4[brow];
        float4 nb = xyz4[sidx[m]];
        float rx = p.x - nb.x, ry = p.y - nb.y, rz = p.z - nb.z;
        for (int c0 = 0; c0 < 64; c0 += 8) {
            bf16x8 v;
#pragma unroll
            for (int cc = 0; cc < 8; cc++) {
                int c = c0 + cc;
                float h = sdw1[192 + c] + rx * sdw1[c] + ry * sdw1[64 + c] + rz * sdw1[128 + c];
                v[cc] = (short)f2bf(fmaxf(h, 0.f));
            }
            *(bf16x8*)&sA[m * 72 + c0] = v;
        }
    }

    int m0 = w * 64;
    bf16x8 af[4][2];

#pragma unroll
    for (int mt = 0; mt < 4; mt++)
#pragma unroll
        for (int k2 = 0; k2 < 2; k2++)
            af[mt][k2] = *(const bf16x8*)&sA[(m0 + mt * 16 + col) * 72 + quad * 8 + k2 * 32];

    f32x4 pos[4][4];
#pragma unroll
    for (int nt = 0; nt < 4; nt++) {
        float bias = db2[nt * 16 + col];
        bf16x8 b0, b1;
        {
            const unsigned short* p0 = &sWd2[(nt * 16 + col) * 68 + quad * 8];
            u16x4 l0 = *(const u16x4*)p0, h0 = *(const u16x4*)(p0 + 4);
            u16x4 l1 = *(const u16x4*)(p0 + 32), h1 = *(const u16x4*)(p0 + 36);
#pragma unroll
            for (int z = 0; z < 4; z++) { b0[z] = (short)l0[z]; b0[z+4] = (short)h0[z]; b1[z] = (short)l1[z]; b1[z+4] = (short)h1[z]; }
        }
#pragma unroll
        for (int mt = 0; mt < 4; mt++) {
            f32x4 acc = {bias, bias, bias, bias};
            acc = __builtin_amdgcn_mfma_f32_16x16x32_bf16(af[mt][0], b0, acc, 0, 0, 0);
            acc = __builtin_amdgcn_mfma_f32_16x16x32_bf16(af[mt][1], b1, acc, 0, 0, 0);
            pos[mt][nt] = acc;
        }
    }

#pragma unroll
    for (int mt = 0; mt < 4; mt++) {
        int row = r0 + w * 4 + mt;
        int gx[4];
#pragma unroll
        for (int r = 0; r < 4; r++) gx[r] = sidx[w * 64 + mt * 16 + quad * 4 + r];
#pragma unroll
        for (int nt = 0; nt < 4; nt++) {
            int c = nt * 16 + col;
            float qv = Q[row * 64 + c];
#pragma unroll
            for (int r = 0; r < 4; r++) {
                float tv = qv - Kf[gx[r] * 64 + c] + pos[mt][nt][r];
                sA[(m0 + mt * 16 + quad * 4 + r) * 72 + c] = f2bf(tv);
            }
        }
    }

#pragma unroll
    for (int mt = 0; mt < 4; mt++)
#pragma unroll
        for (int k2 = 0; k2 < 2; k2++)
            af[mt][k2] = *(const bf16x8*)&sA[(m0 + mt * 16 + col) * 72 + quad * 8 + k2 * 32];

    f32x4 cc4[4][4];
#pragma unroll
    for (int nt = 0; nt < 4; nt++) {
        float bias = gb1[nt * 16 + col];
        bf16x8 b0, b1;
        {
            const unsigned short* p0 = &sWg1[(nt * 16 + col) * 68 + quad * 8];
            u16x4 l0 = *(const u16x4*)p0, h0 = *(const u16x4*)(p0 + 4);
            u16x4 l1 = *(const u16x4*)(p0 + 32), h1 = *(const u16x4*)(p0 + 36);
#pragma unroll
            for (int z = 0; z < 4; z++) { b0[z] = (short)l0[z]; b0[z+4] = (short)h0[z]; b1[z] = (short)l1[z]; b1[z+4] = (short)h1[z]; }
        }
#pragma unroll
        for (int mt = 0; mt < 4; mt++) {
            f32x4 acc = {bias, bias, bias, bias};
            acc = __builtin_amdgcn_mfma_f32_16x16x32_bf16(af[mt][0], b0, acc, 0, 0, 0);
            acc = __builtin_amdgcn_mfma_f32_16x16x32_bf16(af[mt][1], b1, acc, 0, 0, 0);
            cc4[mt][nt] = acc;
        }
    }
#pragma unroll
    for (int mt = 0; mt < 4; mt++)
#pragma unroll
        for (int nt = 0; nt < 4; nt++)
#pragma unroll
            for (int r = 0; r < 4; r++)
                sA[(m0 + mt * 16 + quad * 4 + r) * 72 + nt * 16 + col] = f2bf(fmaxf(cc4[mt][nt][r], 0.f));

#pragma unroll
    for (int mt = 0; mt < 4; mt++)
#pragma unroll
        for (int k2 = 0; k2 < 2; k2++)
            af[mt][k2] = *(const bf16x8*)&sA[(m0 + mt * 16 + col) * 72 + quad * 8 + k2 * 32];

#pragma unroll
    for (int nt = 0; nt < 4; nt++) {
        bf16x8 b0, b1;
        {
            const unsigned short* p0 = &sWg2[(nt * 16 + col) * 68 + quad * 8];
            u16x4 l0 = *(const u16x4*)p0, h0 = *(const u16x4*)(p0 + 4);
            u16x4 l1 = *(const u16x4*)(p0 + 32), h1 = *(const u16x4*)(p0 + 36);
#pragma unroll
            for (int z = 0; z < 4; z++) { b0[z] = (short)l0[z]; b0[z+4] = (short)h0[z]; b1[z] = (short)l1[z]; b1[z+4] = (short)h1[z]; }
        }
#pragma unroll
        for (int mt = 0; mt < 4; mt++) {
            f32x4 acc = {0.f, 0.f, 0.f, 0.f};
            acc = __builtin_amdgcn_mfma_f32_16x16x32_bf16(af[mt][0], b0, acc, 0, 0, 0);
            acc = __builtin_amdgcn_mfma_f32_16x16x32_bf16(af[mt][1], b1, acc, 0, 0, 0);
            cc4[mt][nt] = acc;
        }
    }

    float bs[4] = {0.f, 0.f, 0.f, 0.f}, bq[4] = {0.f, 0.f, 0.f, 0.f};
#pragma unroll
    for (int mt = 0; mt < 4; mt++) {
        int row = r0 + w * 4 + mt;
        int gx[4];
#pragma unroll
        for (int r = 0; r < 4; r++) gx[r] = sidx[w * 64 + mt * 16 + quad * 4 + r];
#pragma unroll
        for (int nt = 0; nt < 4; nt++) {
            int c = nt * 16 + col;
            f32x4 a = cc4[mt][nt];
            float mx = fmaxf(fmaxf(a[0], a[1]), fmaxf(a[2], a[3]));
            mx = fmaxf(mx, __shfl_xor(mx, 16, 64));
            mx = fmaxf(mx, __shfl_xor(mx, 32, 64));
            float es = 0.f, ws = 0.f;
#pragma unroll
            for (int r = 0; r < 4; r++) {
                float e = __expf(a[r] - mx);
                float vv = Vf[gx[r] * 64 + c] + pos[mt][nt][r];
                es += e;
                ws = fmaf(e, vv, ws);
            }
            es += __shfl_xor(es, 16, 64); es += __shfl_xor(es, 32, 64);
            ws += __shfl_xor(ws, 16, 64); ws += __shfl_xor(ws, 32, 64);
            if (quad == 0) {
                float v = ws / es + feats[row * 64 + c];
                res[row * 64 + c] = v;
                bs[nt] += v;
                bq[nt] = fmaf(v, v, bq[nt]);
            }
        }
    }

    __syncthreads();
    float* fbuf = (float*)sA;
    if (quad == 0) {
#pragma unroll
        for (int nt = 0; nt < 4; nt++) {
            int c = nt * 16 + col;
            fbuf[w * 64 + c] = bs[nt];
            fbuf[256 + w * 64 + c] = bq[nt];
        }
    }
    __syncthreads();
    if (tid < 64) {
        float s = fbuf[tid] + fbuf[64 + tid] + fbuf[128 + tid] + fbuf[192 + tid];
        atomicAdd(&accum[tid], s);
    } else if (tid < 128) {
        int c = tid - 64;
        float q = fbuf[256 + c] + fbuf[320 + c] + fbuf[384 + c] + fbuf[448 + c];
        atomicAdd(&accum[64 + c], q);
    }
}

// ---------------- batchnorm apply + fp32 output (float4 vectorized) ----------
__global__ __launch_bounds__(256) void norm_kernel(const float4* __restrict__ res,
                                                   const float* __restrict__ accum,
                                                   const float* __restrict__ bng,
                                                   const float* __restrict__ bnb,
                                                   float4* __restrict__ out) {
    int i = blockIdx.x * 256 + threadIdx.x;   // float4 index
    int c0 = (i & 15) * 4;                    // channel of element 0
    float4 v = res[i];
    float4 o;
    float m0 = accum[c0],     q0 = accum[64 + c0];
    float m1 = accum[c0 + 1], q1 = accum[64 + c0 + 1];
    float m2 = accum[c0 + 2], q2 = accum[64 + c0 + 2];
    float m3 = accum[c0 + 3], q3 = accum[64 + c0 + 3];
    float mean, var, sc;
    mean = m0 * (1.f / 16384.f); var = q0 * (1.f / 16384.f) - mean * mean;
    sc = rsqrtf(var + 1e-5f) * bng[c0];     o.x = fmaf(v.x - mean, sc, bnb[c0]);
    mean = m1 * (1.f / 16384.f); var = q1 * (1.f / 16384.f) - mean * mean;
    sc = rsqrtf(var + 1e-5f) * bng[c0 + 1]; o.y = fmaf(v.y - mean, sc, bnb[c0 + 1]);
    mean = m2 * (1.f / 16384.f); var = q2 * (1.f / 16384.f) - mean * mean;
    sc = rsqrtf(var + 1e-5f) * bng[c0 + 2]; o.z = fmaf(v.z - mean, sc, bnb[c0 + 2]);
    mean = m3 * (1.f / 16384.f); var = q3 * (1.f / 16384.f) - mean * mean;
    sc = rsqrtf(var + 1e-5f) * bng[c0 + 3]; o.w = fmaf(v.w - mean, sc, bnb[c0 + 3]);
    out[i] = o;
}

extern "C" void kernel_launch(void* const* d_in, const int* in_sizes, int n_in,
                              void* d_out, int out_size, void* d_ws, size_t ws_size,
                              hipStream_t stream) {
    const float* xyz  = (const float*)d_in[0];
    const float* feats = (const float*)d_in[1];
    const float* w_qs = (const float*)d_in[2];
    const float* w_ks = (const float*)d_in[3];
    const float* w_vs = (const float*)d_in[4];
    const float* dw1 = (const float*)d_in[5];
    const float* db1 = (const float*)d_in[6];
    const float* dw2 = (const float*)d_in[7];
    const float* db2 = (const float*)d_in[8];
    const float* gw1 = (const float*)d_in[9];
    const float* gb1 = (const float*)d_in[10];
    const float* gw2 = (const float*)d_in[11];
    const float* bng = (const float*)d_in[13];
    const float* bnb = (const float*)d_in[14];

    char* ws = (char*)d_ws;
    float4* xyz4 = (float4*)ws;                        // 256 KB
    int* knn    = (int*)(ws + 262144);                 // 1 MB
    float* Q    = (float*)(ws + 1310720);              // 4 MB
    float* Kf   = (float*)(ws + 5505024);              // 4 MB
    float* Vf   = (float*)(ws + 9699328);              // 4 MB
    float* res  = (float*)(ws + 13893632);             // 4 MB
    float* accum = (float*)(ws + 18087936);            // 512 B
    unsigned short* wbf = (unsigned short*)(ws + 18088448); // 24 KB bf16 qkv weights

    hipMemsetAsync(accum, 0, 512, stream);
    pack_prep<<<67, 256, 0, stream>>>(xyz, xyz4, w_qs, w_ks, w_vs, wbf);
    knnqkv_kernel<<<2304, 256, 0, stream>>>(xyz4, knn, feats, wbf, Q, Kf, Vf);
    attn_mfma<<<1024, 256, 0, stream>>>(xyz4, knn, Q, Kf, Vf, feats,
                                        dw1, db1, dw2, db2, gw1, gb1, gw2, res, accum);
    norm_kernel<<<1024, 256, 0, stream>>>((const float4*)res, accum, bng, bnb, (float4*)d_out);
}